// Round 1
// baseline (241.627 us; speedup 1.0000x reference)
//
#include <hip/hip_runtime.h>

// ChunkwiseRetention: B=8 T=1024 C=1024 NH=16 HD=64
// out[b,t,h*64+d] = GN_b(r)[...]*w[h]+bias[h],  r = (QK^T ∘ decay)V + 1024*Q@past_kv
// current_kv[h] = gamma_h*past_kv[h] + mean_b(K^T V)

#define TKN 8192
#define N3  3072

typedef short short8 __attribute__((ext_vector_type(8)));
typedef float f32x4 __attribute__((ext_vector_type(4)));

static __device__ __forceinline__ unsigned short f2bf(float f){
  unsigned int u = __float_as_uint(f);
  u += 0x7FFFu + ((u >> 16) & 1u);
  return (unsigned short)(u >> 16);
}
static __device__ __forceinline__ float bf2f(unsigned short s){
  return __uint_as_float(((unsigned int)s) << 16);
}
static __device__ __forceinline__ void g2lds16(const void* g, void* l){
  __builtin_amdgcn_global_load_lds(
      (const __attribute__((address_space(1))) unsigned int*)g,
      (__attribute__((address_space(3))) unsigned int*)l, 16, 0, 0);
}

// ---------------- conversions ----------------
__global__ __launch_bounds__(256) void k_cvt_x(const float* __restrict__ x,
                                               unsigned short* __restrict__ xb){
  const int n4 = TKN*1024/4;
  for (int idx = blockIdx.x*256 + threadIdx.x; idx < n4; idx += gridDim.x*256){
    float4 v = reinterpret_cast<const float4*>(x)[idx];
    ushort4 o;
    o.x = f2bf(v.x); o.y = f2bf(v.y); o.z = f2bf(v.z); o.w = f2bf(v.w);
    reinterpret_cast<ushort4*>(xb)[idx] = o;
  }
}

// W [1024][3072] f32 -> WT [3072][1024] bf16  (LDS tile transpose)
__global__ __launch_bounds__(256) void k_cvt_w(const float* __restrict__ w,
                                               unsigned short* __restrict__ wt){
  __shared__ float tile[64][65];
  const int n0 = blockIdx.x*64, k0 = blockIdx.y*64;
  const int tn = threadIdx.x & 63, t4 = threadIdx.x >> 6;
  for (int kk = t4; kk < 64; kk += 4)
    tile[kk][tn] = w[(k0+kk)*N3 + n0 + tn];
  __syncthreads();
  for (int nn = t4; nn < 64; nn += 4)
    wt[(n0+nn)*1024 + k0 + tn] = f2bf(tile[tn][nn]);
}

// pkt[h][e][d] = past_kv[h][d][e] * 1024  (bf16)
__global__ __launch_bounds__(256) void k_cvt_pk(const float* __restrict__ pk,
                                                unsigned short* __restrict__ pkt){
  int i = blockIdx.x*256 + threadIdx.x;           // 65536 total
  int h = i >> 12, e = (i >> 6) & 63, d = i & 63;
  pkt[i] = f2bf(pk[(h<<12) + (d<<6) + e] * 1024.0f);
}

// ---------------- QKV GEMM (bf16 MFMA, 128x128 tile, BK=64) ----------------
__global__ __launch_bounds__(256) void k_gemm(const unsigned short* __restrict__ A,
                                              const unsigned short* __restrict__ Bt,
                                              unsigned short* __restrict__ qb,
                                              unsigned short* __restrict__ kb,
                                              unsigned short* __restrict__ vtb){
  __shared__ unsigned short smem[17408];          // As(8192)+Bs(8192) | Cs 128x136
  unsigned short* As = smem;
  unsigned short* Bs = smem + 8192;
  const int tid = threadIdx.x;
  const int lane = tid & 63, wid = tid >> 6;
  const int wm = wid >> 1, wn = wid & 1;
  const int m0 = blockIdx.y * 128;
  const int n0 = blockIdx.x * 128;

  f32x4 acc[4][4] = {};
  const int srow = tid >> 3, schunk = tid & 7;

  for (int kt = 0; kt < 16; ++kt){
    const int k0 = kt * 64;
    __syncthreads();
    for (int c = 0; c < 4; ++c){
      int r = c*32 + srow;
      int src = schunk ^ (r & 7);                 // pre-swizzled global source
      g2lds16(A  + (long)(m0 + r)*1024 + k0 + src*8, (char*)As + c*4096 + tid*16);
      g2lds16(Bt + (long)(n0 + r)*1024 + k0 + src*8, (char*)Bs + c*4096 + tid*16);
    }
    asm volatile("s_waitcnt vmcnt(0)" ::: "memory");
    __syncthreads();
    #pragma unroll
    for (int kk = 0; kk < 2; ++kk){
      short8 a[4], b[4];
      #pragma unroll
      for (int i = 0; i < 4; ++i){
        int ra = wm*64 + i*16 + (lane & 15);
        int sa = (kk*4 + (lane >> 4)) ^ (ra & 7);
        a[i] = *reinterpret_cast<const short8*>((const char*)As + ra*128 + sa*16);
        int rb = wn*64 + i*16 + (lane & 15);
        int sb = (kk*4 + (lane >> 4)) ^ (rb & 7);
        b[i] = *reinterpret_cast<const short8*>((const char*)Bs + rb*128 + sb*16);
      }
      #pragma unroll
      for (int i = 0; i < 4; ++i)
        #pragma unroll
        for (int j = 0; j < 4; ++j)
          acc[i][j] = __builtin_amdgcn_mfma_f32_16x16x32_bf16(a[i], b[j], acc[i][j], 0, 0, 0);
    }
  }
  __syncthreads();
  // repack C through LDS (bf16), then scatter heads
  unsigned short* Cs = smem;                      // [128][136]
  #pragma unroll
  for (int i = 0; i < 4; ++i)
    #pragma unroll
    for (int j = 0; j < 4; ++j)
      #pragma unroll
      for (int r = 0; r < 4; ++r){
        int m = wm*64 + i*16 + (lane>>4)*4 + r;
        int n = wn*64 + j*16 + (lane & 15);
        Cs[m*136 + n] = f2bf(acc[i][j][r]);
      }
  __syncthreads();
  const int bb = m0 >> 10;                        // batch (128 | 1024)
  const int t0 = m0 & 1023;
  const int which = n0 >> 10;                     // 0=q 1=k 2=v
  const int cb = n0 & 1023;
  if (which < 2){
    unsigned short* dst = (which == 0) ? qb : kb; // [b][h][t][d]
    for (int e = tid; e < 2048; e += 256){
      int row = e >> 4;
      int c = (e & 15) * 8;
      uint4 v = *reinterpret_cast<const uint4*>(&Cs[row*136 + c]);
      int cc = cb + c;
      int h = cc >> 6, d = cc & 63;
      *reinterpret_cast<uint4*>(&dst[((long)(bb*16 + h)*1024 + t0 + row)*64 + d]) = v;
    }
  } else {                                        // V transposed: [b][h][d][t]
    for (int e = tid; e < 2048; e += 256){
      int c = e >> 4;
      int rg = e & 15;
      union { unsigned short u[8]; uint4 v; } p;
      #pragma unroll
      for (int r = 0; r < 8; ++r) p.u[r] = Cs[(rg*8 + r)*136 + c];
      int cc = cb + c;
      int h = cc >> 6, d = cc & 63;
      *reinterpret_cast<uint4*>(&vtb[((long)(bb*16 + h)*64 + d)*1024 + t0 + rg*8]) = p.v;
    }
  }
}

// ---------------- decay-masked attention + cross term ----------------
__global__ __launch_bounds__(256) void k_attn(const unsigned short* __restrict__ qb,
                                              const unsigned short* __restrict__ kb,
                                              const unsigned short* __restrict__ vtb,
                                              const unsigned short* __restrict__ pkt,
                                              float* __restrict__ rr){
  __shared__ unsigned short Qs[8192];             // [128][64] swizzled
  __shared__ unsigned short Ks[4096];             // [kv or e][64] swizzled
  __shared__ unsigned short Vs[4096];             // [d][64 t] swizzled
  __shared__ unsigned short Ps[8192];             // [128][64] swizzled, wave-local
  const int qt = blockIdx.x;
  const int bh = blockIdx.y;
  const int h = bh & 15;
  const int tid = threadIdx.x;
  const int lane = tid & 63, wid = tid >> 6;
  const int t0 = qt * 128;
  const unsigned short* qp = qb + (long)bh*65536;
  const unsigned short* kp = kb + (long)bh*65536;
  const unsigned short* vp = vtb + (long)bh*65536;
  const float gamma = 1.0f - exp2f(-5.0f - (float)h);
  const float lg = log2f(gamma);

  const int srow = tid >> 3, schunk = tid & 7;
  for (int c = 0; c < 4; ++c){
    int r = c*32 + srow;
    int src = schunk ^ (r & 7);
    g2lds16(qp + (long)(t0 + r)*64 + src*8, (char*)Qs + c*4096 + tid*16);
  }
  for (int c = 0; c < 2; ++c){
    int r = c*32 + srow;
    int src = schunk ^ (r & 7);
    g2lds16(pkt + (long)(h*64 + r)*64 + src*8, (char*)Ks + c*4096 + tid*16);
  }
  asm volatile("s_waitcnt vmcnt(0)" ::: "memory");
  __syncthreads();

  short8 aq[2][2];
  #pragma unroll
  for (int mf = 0; mf < 2; ++mf)
    #pragma unroll
    for (int kk = 0; kk < 2; ++kk){
      int r = wid*32 + mf*16 + (lane & 15);
      int sl = (kk*4 + (lane >> 4)) ^ (r & 7);
      aq[mf][kk] = *reinterpret_cast<const short8*>((const char*)Qs + r*128 + sl*16);
    }

  f32x4 o[2][4] = {};                             // init with cross = Q @ (pk^T*1024)
  #pragma unroll
  for (int kk = 0; kk < 2; ++kk){
    short8 bpk[4];
    #pragma unroll
    for (int nf = 0; nf < 4; ++nf){
      int r = nf*16 + (lane & 15);
      int sl = (kk*4 + (lane >> 4)) ^ (r & 7);
      bpk[nf] = *reinterpret_cast<const short8*>((const char*)Ks + r*128 + sl*16);
    }
    #pragma unroll
    for (int mf = 0; mf < 2; ++mf)
      #pragma unroll
      for (int nf = 0; nf < 4; ++nf)
        o[mf][nf] = __builtin_amdgcn_mfma_f32_16x16x32_bf16(aq[mf][kk], bpk[nf], o[mf][nf], 0,0,0);
  }

  const int jmax = 2*qt + 1;
  for (int j = 0; j <= jmax; ++j){
    const int kv0 = j*64;
    __syncthreads();
    for (int c = 0; c < 2; ++c){
      int r = c*32 + srow;
      int src = schunk ^ (r & 7);
      g2lds16(kp + (long)(kv0 + r)*64 + src*8, (char*)Ks + c*4096 + tid*16);
      g2lds16(vp + (long)r*1024 + kv0 + src*8, (char*)Vs + c*4096 + tid*16);
    }
    asm volatile("s_waitcnt vmcnt(0)" ::: "memory");
    __syncthreads();

    f32x4 s[2][4] = {};
    #pragma unroll
    for (int kk = 0; kk < 2; ++kk){
      short8 bk[4];
      #pragma unroll
      for (int nf = 0; nf < 4; ++nf){
        int r = nf*16 + (lane & 15);
        int sl = (kk*4 + (lane >> 4)) ^ (r & 7);
        bk[nf] = *reinterpret_cast<const short8*>((const char*)Ks + r*128 + sl*16);
      }
      #pragma unroll
      for (int mf = 0; mf < 2; ++mf)
        #pragma unroll
        for (int nf = 0; nf < 4; ++nf)
          s[mf][nf] = __builtin_amdgcn_mfma_f32_16x16x32_bf16(aq[mf][kk], bk[nf], s[mf][nf], 0,0,0);
    }
    // decay * causal mask -> P (bf16, wave-local swizzled region)
    #pragma unroll
    for (int mf = 0; mf < 2; ++mf)
      #pragma unroll
      for (int nf = 0; nf < 4; ++nf){
        int tj = kv0 + nf*16 + (lane & 15);
        int mB = wid*32 + mf*16 + ((lane >> 4) << 2);
        int n = nf*16 + (lane & 15);
        #pragma unroll
        for (int r = 0; r < 4; ++r){
          int ti = t0 + mB + r;
          int diff = ti - tj;
          float wgt = exp2f(lg * (float)diff);
          float val = (diff >= 0) ? s[mf][nf][r] * wgt : 0.0f;
          int byte = ((mB + r)*128 + n*2) ^ (((mB + r) & 7) << 4);
          *(unsigned short*)((char*)Ps + byte) = f2bf(val);
        }
      }
    // O += P @ V
    #pragma unroll
    for (int kk = 0; kk < 2; ++kk){
      short8 ap[2], bv[4];
      #pragma unroll
      for (int mf = 0; mf < 2; ++mf){
        int r = wid*32 + mf*16 + (lane & 15);
        int sl = (kk*4 + (lane >> 4)) ^ (r & 7);
        ap[mf] = *reinterpret_cast<const short8*>((const char*)Ps + r*128 + sl*16);
      }
      #pragma unroll
      for (int nf = 0; nf < 4; ++nf){
        int r = nf*16 + (lane & 15);
        int sl = (kk*4 + (lane >> 4)) ^ (r & 7);
        bv[nf] = *reinterpret_cast<const short8*>((const char*)Vs + r*128 + sl*16);
      }
      #pragma unroll
      for (int mf = 0; mf < 2; ++mf)
        #pragma unroll
        for (int nf = 0; nf < 4; ++nf)
          o[mf][nf] = __builtin_amdgcn_mfma_f32_16x16x32_bf16(ap[mf], bv[nf], o[mf][nf], 0,0,0);
    }
  }
  float* rp = rr + (long)bh*65536;
  #pragma unroll
  for (int mf = 0; mf < 2; ++mf)
    #pragma unroll
    for (int nf = 0; nf < 4; ++nf)
      #pragma unroll
      for (int r = 0; r < 4; ++r){
        int t = t0 + wid*32 + mf*16 + (lane>>4)*4 + r;
        int d = nf*16 + (lane & 15);
        rp[t*64 + d] = o[mf][nf][r];
      }
}

// ---------------- K^T V partials ----------------
__global__ __launch_bounds__(256) void k_kvpart(const unsigned short* __restrict__ kb,
                                                const unsigned short* __restrict__ vtb,
                                                float* __restrict__ part){
  __shared__ unsigned short Kt[64*64];            // [t][d]
  __shared__ unsigned int   Vt32[64*33];          // [e][t] padded rows (66 ushorts)
  const int tc = blockIdx.x, bh = blockIdx.y;
  const int tid = threadIdx.x;
  const int d0 = (tid >> 4) << 2;
  const int e0 = (tid & 15) << 2;
  const unsigned short* kp = kb + (long)bh*65536;
  const unsigned short* vp = vtb + (long)bh*65536;
  float acc[4][4] = {{0.f}};
  for (int tt = 0; tt < 4; ++tt){
    const int tb = tc*256 + tt*64;
    __syncthreads();
    {
      int rr0 = tid >> 3, off = (tid & 7) * 8;
      for (int c = 0; c < 2; ++c){
        int r = c*32 + rr0;
        *reinterpret_cast<uint4*>(&Kt[r*64 + off]) =
            *reinterpret_cast<const uint4*>(&kp[(long)(tb + r)*64 + off]);
        uint4 vv = *reinterpret_cast<const uint4*>(&vp[(long)r*1024 + tb + off]);
        unsigned int* dv = &Vt32[r*33 + (off >> 1)];
        dv[0] = vv.x; dv[1] = vv.y; dv[2] = vv.z; dv[3] = vv.w;
      }
    }
    __syncthreads();
    const unsigned short* Vt = (const unsigned short*)Vt32;
    for (int t = 0; t < 64; ++t){
      float kv[4], vv[4];
      #pragma unroll
      for (int i = 0; i < 4; ++i) kv[i] = bf2f(Kt[t*64 + d0 + i]);
      #pragma unroll
      for (int i = 0; i < 4; ++i) vv[i] = bf2f(Vt[(e0 + i)*66 + t]);
      #pragma unroll
      for (int i = 0; i < 4; ++i)
        #pragma unroll
        for (int j = 0; j < 4; ++j) acc[i][j] += kv[i]*vv[j];
    }
  }
  float* pp = part + ((long)(tc*128 + bh) << 12);
  for (int i = 0; i < 4; ++i)
    for (int j = 0; j < 4; ++j)
      pp[(d0+i)*64 + e0 + j] = acc[i][j];
}

__global__ __launch_bounds__(256) void k_kvfin(const float* __restrict__ part,
                                               const float* __restrict__ pk,
                                               float* __restrict__ okv){
  int i = blockIdx.x*256 + threadIdx.x;           // 65536
  int h = i >> 12;
  float acc = 0.f;
  for (int tc = 0; tc < 4; ++tc)
    for (int b = 0; b < 8; ++b)
      acc += part[((long)(tc*128 + b*16 + h) << 12) + (i & 4095)];
  float gamma = 1.0f - exp2f(-5.0f - (float)h);
  okv[i] = gamma * pk[i] + acc * 0.125f;
}

// ---------------- GroupNorm ----------------
__global__ __launch_bounds__(256) void k_gnr1(const float* __restrict__ r,
                                              float* __restrict__ part){
  __shared__ float red[2][4];
  const int blk = blockIdx.x;                     // b = blk>>5, g = blk&31
  const float* p = r + (long)blk*32768;
  float s = 0.f, sq = 0.f;
  for (int i = threadIdx.x; i < 8192; i += 256){
    float4 v = reinterpret_cast<const float4*>(p)[i];
    s  += v.x + v.y + v.z + v.w;
    sq += v.x*v.x + v.y*v.y + v.z*v.z + v.w*v.w;
  }
  #pragma unroll
  for (int off = 32; off > 0; off >>= 1){
    s  += __shfl_down(s, off);
    sq += __shfl_down(sq, off);
  }
  if ((threadIdx.x & 63) == 0){ red[0][threadIdx.x>>6] = s; red[1][threadIdx.x>>6] = sq; }
  __syncthreads();
  if (threadIdx.x == 0){
    part[blk*2]   = red[0][0]+red[0][1]+red[0][2]+red[0][3];
    part[blk*2+1] = red[1][0]+red[1][1]+red[1][2]+red[1][3];
  }
}

__global__ __launch_bounds__(64) void k_gnr2(const float* __restrict__ part,
                                             float* __restrict__ musig){
  int b = threadIdx.x;
  if (b < 8){
    float S = 0.f, Q = 0.f;
    for (int g = 0; g < 32; ++g){ S += part[(b*32+g)*2]; Q += part[(b*32+g)*2+1]; }
    float mu  = S * (1.0f/1048576.0f);
    float var = Q * (1.0f/1048576.0f) - mu*mu;
    musig[b*2]   = mu;
    musig[b*2+1] = rsqrtf(var + 1e-5f);
  }
}

__global__ __launch_bounds__(256) void k_gnnorm(const float* __restrict__ r,
                                                const float* __restrict__ musig,
                                                const float* __restrict__ gw,
                                                const float* __restrict__ gb,
                                                float* __restrict__ out){
  const int n4 = TKN*1024/4;
  for (int idx = blockIdx.x*256 + threadIdx.x; idx < n4; idx += gridDim.x*256){
    int o = idx*4;
    int c = o & 1023;
    int t = (o >> 10) & 1023;
    int b = o >> 20;
    int h = c >> 6, d = c & 63;
    float4 v = *reinterpret_cast<const float4*>(&r[((long)(b*16 + h) << 16) + t*64 + d]);
    float mu = musig[b*2], rs = musig[b*2+1];
    float wv = gw[h], bv = gb[h];
    float4 ov;
    ov.x = (v.x - mu)*rs*wv + bv;
    ov.y = (v.y - mu)*rs*wv + bv;
    ov.z = (v.z - mu)*rs*wv + bv;
    ov.w = (v.w - mu)*rs*wv + bv;
    reinterpret_cast<float4*>(out)[idx] = ov;
  }
}

extern "C" void kernel_launch(void* const* d_in, const int* in_sizes, int n_in,
                              void* d_out, int out_size, void* d_ws, size_t ws_size,
                              hipStream_t stream){
  const float* x  = (const float*)d_in[0];
  const float* pk = (const float*)d_in[1];
  const float* w  = (const float*)d_in[2];
  const float* gw = (const float*)d_in[3];
  const float* gb = (const float*)d_in[4];
  float* out = (float*)d_out;
  char* ws = (char*)d_ws;

  unsigned short* Xb  = (unsigned short*)(ws);                 // 16,777,216
  unsigned short* WTb = (unsigned short*)(ws + 16777216);      //  6,291,456
  unsigned short* Qb  = (unsigned short*)(ws + 23068672);      // 16,777,216
  unsigned short* Kb  = (unsigned short*)(ws + 39845888);      // 16,777,216
  unsigned short* VTb = (unsigned short*)(ws + 56623104);      // 16,777,216
  unsigned short* PKt = (unsigned short*)(ws + 73400320);      //    131,072
  float* R   = (float*)(ws + 73531392);                        // 33,554,432
  float* KVp = (float*)(ws + 107085824);                       //  8,388,608
  float* GNp = (float*)(ws + 115474432);                       //      2,048
  float* MuS = (float*)(ws + 115476480);                       //         64

  k_cvt_x  <<<dim3(2048),    dim3(256), 0, stream>>>(x, Xb);
  k_cvt_w  <<<dim3(48, 16),  dim3(256), 0, stream>>>(w, WTb);
  k_cvt_pk <<<dim3(256),     dim3(256), 0, stream>>>(pk, PKt);
  k_gemm   <<<dim3(24, 64),  dim3(256), 0, stream>>>(Xb, WTb, Qb, Kb, VTb);
  k_attn   <<<dim3(8, 128),  dim3(256), 0, stream>>>(Qb, Kb, VTb, PKt, R);
  k_kvpart <<<dim3(4, 128),  dim3(256), 0, stream>>>(Kb, VTb, KVp);
  k_kvfin  <<<dim3(256),     dim3(256), 0, stream>>>(KVp, pk, out + 8388608);
  k_gnr1   <<<dim3(256),     dim3(256), 0, stream>>>(R, GNp);
  k_gnr2   <<<dim3(1),       dim3(64),  0, stream>>>(GNp, MuS);
  k_gnnorm <<<dim3(2048),    dim3(256), 0, stream>>>(R, MuS, gw, gb, out);
}

// Round 2
// 206.436 us; speedup vs baseline: 1.1705x; 1.1705x over previous
//
#include <hip/hip_runtime.h>

// ChunkwiseRetention: B=8 T=1024 C=1024 NH=16 HD=64
// out[b,t,h*64+d] = GN_b(r)*w[h]+bias[h],  r = (QK^T ∘ decay)V + 1024*Q@past_kv
// current_kv[h] = gamma_h*past_kv[h] + mean_b(K^T V)

#define TKN 8192
#define N3  3072

typedef short short8 __attribute__((ext_vector_type(8)));
typedef float f32x4 __attribute__((ext_vector_type(4)));

static __device__ __forceinline__ unsigned short f2bf(float f){
  unsigned int u = __float_as_uint(f);
  u += 0x7FFFu + ((u >> 16) & 1u);
  return (unsigned short)(u >> 16);
}
static __device__ __forceinline__ float bf2f(unsigned short s){
  return __uint_as_float(((unsigned int)s) << 16);
}
static __device__ __forceinline__ void g2lds16(const void* g, void* l){
  __builtin_amdgcn_global_load_lds(
      (const __attribute__((address_space(1))) unsigned int*)g,
      (__attribute__((address_space(3))) unsigned int*)l, 16, 0, 0);
}

// ---------------- conversions ----------------
__global__ __launch_bounds__(256) void k_cvt_x(const float* __restrict__ x,
                                               unsigned short* __restrict__ xb){
  const int n4 = TKN*1024/4;
  for (int idx = blockIdx.x*256 + threadIdx.x; idx < n4; idx += gridDim.x*256){
    float4 v = reinterpret_cast<const float4*>(x)[idx];
    ushort4 o;
    o.x = f2bf(v.x); o.y = f2bf(v.y); o.z = f2bf(v.z); o.w = f2bf(v.w);
    reinterpret_cast<ushort4*>(xb)[idx] = o;
  }
}

// W [1024][3072] f32 -> WT [3072][1024] bf16
__global__ __launch_bounds__(256) void k_cvt_w(const float* __restrict__ w,
                                               unsigned short* __restrict__ wt){
  __shared__ float tile[64][65];
  const int n0 = blockIdx.x*64, k0 = blockIdx.y*64;
  const int tn = threadIdx.x & 63, t4 = threadIdx.x >> 6;
  for (int kk = t4; kk < 64; kk += 4)
    tile[kk][tn] = w[(k0+kk)*N3 + n0 + tn];
  __syncthreads();
  for (int nn = t4; nn < 64; nn += 4)
    wt[(n0+nn)*1024 + k0 + tn] = f2bf(tile[tn][nn]);
}

// pkt[h][e][d] = past_kv[h][d][e] * 1024  (bf16)
__global__ __launch_bounds__(256) void k_cvt_pk(const float* __restrict__ pk,
                                                unsigned short* __restrict__ pkt){
  int i = blockIdx.x*256 + threadIdx.x;
  int h = i >> 12, e = (i >> 6) & 63, d = i & 63;
  pkt[i] = f2bf(pk[(h<<12) + (d<<6) + e] * 1024.0f);
}

// ---------------- QKV GEMM (bf16 MFMA, 128x128 tile, BK=64) ----------------
__global__ __launch_bounds__(256) void k_gemm(const unsigned short* __restrict__ A,
                                              const unsigned short* __restrict__ Bt,
                                              unsigned short* __restrict__ qb,
                                              unsigned short* __restrict__ kb,
                                              unsigned short* __restrict__ ktb,
                                              unsigned short* __restrict__ vtb){
  __shared__ unsigned short smem[17408];
  unsigned short* As = smem;
  unsigned short* Bs = smem + 8192;
  const int tid = threadIdx.x;
  const int lane = tid & 63, wid = tid >> 6;
  const int wm = wid >> 1, wn = wid & 1;
  const int m0 = blockIdx.y * 128;
  const int n0 = blockIdx.x * 128;

  f32x4 acc[4][4] = {};
  const int srow = tid >> 3, schunk = tid & 7;

  for (int kt = 0; kt < 16; ++kt){
    const int k0 = kt * 64;
    __syncthreads();
    for (int c = 0; c < 4; ++c){
      int r = c*32 + srow;
      int src = schunk ^ (r & 7);
      g2lds16(A  + (long)(m0 + r)*1024 + k0 + src*8, (char*)As + c*4096 + tid*16);
      g2lds16(Bt + (long)(n0 + r)*1024 + k0 + src*8, (char*)Bs + c*4096 + tid*16);
    }
    asm volatile("s_waitcnt vmcnt(0)" ::: "memory");
    __syncthreads();
    #pragma unroll
    for (int kk = 0; kk < 2; ++kk){
      short8 a[4], b[4];
      #pragma unroll
      for (int i = 0; i < 4; ++i){
        int ra = wm*64 + i*16 + (lane & 15);
        int sa = (kk*4 + (lane >> 4)) ^ (ra & 7);
        a[i] = *reinterpret_cast<const short8*>((const char*)As + ra*128 + sa*16);
        int rb = wn*64 + i*16 + (lane & 15);
        int sb = (kk*4 + (lane >> 4)) ^ (rb & 7);
        b[i] = *reinterpret_cast<const short8*>((const char*)Bs + rb*128 + sb*16);
      }
      #pragma unroll
      for (int i = 0; i < 4; ++i)
        #pragma unroll
        for (int j = 0; j < 4; ++j)
          acc[i][j] = __builtin_amdgcn_mfma_f32_16x16x32_bf16(a[i], b[j], acc[i][j], 0, 0, 0);
    }
  }
  __syncthreads();
  unsigned short* Cs = smem;                      // [128][136]
  #pragma unroll
  for (int i = 0; i < 4; ++i)
    #pragma unroll
    for (int j = 0; j < 4; ++j)
      #pragma unroll
      for (int r = 0; r < 4; ++r){
        int m = wm*64 + i*16 + (lane>>4)*4 + r;
        int n = wn*64 + j*16 + (lane & 15);
        Cs[m*136 + n] = f2bf(acc[i][j][r]);
      }
  __syncthreads();
  const int bb = m0 >> 10;
  const int t0 = m0 & 1023;
  const int which = n0 >> 10;                     // 0=q 1=k 2=v
  const int cb = n0 & 1023;
  if (which < 2){                                 // q,k row-major [b][h][t][d]
    unsigned short* dst = (which == 0) ? qb : kb;
    for (int e = tid; e < 2048; e += 256){
      int row = e >> 4;
      int c = (e & 15) * 8;
      uint4 v = *reinterpret_cast<const uint4*>(&Cs[row*136 + c]);
      int cc = cb + c;
      int h = cc >> 6, d = cc & 63;
      *reinterpret_cast<uint4*>(&dst[((long)(bb*16 + h)*1024 + t0 + row)*64 + d]) = v;
    }
  }
  if (which >= 1){                                // k,v transposed [b][h][d][t]
    unsigned short* dst = (which == 1) ? ktb : vtb;
    for (int e = tid; e < 2048; e += 256){
      int c = e >> 4;
      int rg = e & 15;
      union { unsigned short u[8]; uint4 v; } p;
      #pragma unroll
      for (int r = 0; r < 8; ++r) p.u[r] = Cs[(rg*8 + r)*136 + c];
      int cc = cb + c;
      int h = cc >> 6, d = cc & 63;
      *reinterpret_cast<uint4*>(&dst[((long)(bb*16 + h)*64 + d)*1024 + t0 + rg*8]) = p.v;
    }
  }
}

// ---------------- attention: paired q-tiles, double-buffered K/V ----------------
__global__ __launch_bounds__(256) void k_attn(const unsigned short* __restrict__ qb,
                                              const unsigned short* __restrict__ kb,
                                              const unsigned short* __restrict__ vtb,
                                              const unsigned short* __restrict__ pkt,
                                              unsigned short* __restrict__ rb,
                                              float* __restrict__ gnp){
  __shared__ unsigned short Qs[8192];             // [128][64] swizzled
  __shared__ unsigned short Kd[2][4096];          // double-buffered K tile
  __shared__ unsigned short Vd[2][4096];          // double-buffered V tile
  __shared__ unsigned short Ps[8192];             // P (wave-local) / PKt staging
  __shared__ float gred[2][4];
  const int qpair = blockIdx.x;                   // 0..3
  const int bh = blockIdx.y;
  const int h = bh & 15;
  const int tid = threadIdx.x;
  const int lane = tid & 63, wid = tid >> 6;
  const int n15 = lane & 15, l4 = lane >> 4;
  const unsigned short* qp = qb + (long)bh*65536;
  const unsigned short* kp = kb + (long)bh*65536;
  const unsigned short* vp = vtb + (long)bh*65536;
  const float lg = log2f(1.0f - exp2f(-5.0f - (float)h));
  const int srow = tid >> 3, schunk = tid & 7;

  float cexp[4];
  #pragma unroll
  for (int nf = 0; nf < 4; ++nf)
    cexp[nf] = exp2f(-lg * (float)(nf*16 + n15));   // gamma^{-(col within tile)}

  float gs = 0.f, gq = 0.f;
  unsigned short* rp = rb + (long)bh*65536;

  for (int p = 0; p < 2; ++p){
    const int qt = p ? (7 - qpair) : qpair;       // paired for balance: 18 iters/block
    const int t0 = qt * 128;
    // phase A: stage Q, PKt(->Ps), K0, V0
    for (int c = 0; c < 4; ++c){
      int r = c*32 + srow;
      int src = schunk ^ (r & 7);
      g2lds16(qp + (long)(t0 + r)*64 + src*8, (char*)Qs + c*4096 + tid*16);
    }
    for (int c = 0; c < 2; ++c){
      int r = c*32 + srow;
      int src = schunk ^ (r & 7);
      g2lds16(pkt + (long)(h*64 + r)*64 + src*8, (char*)Ps + c*4096 + tid*16);
      g2lds16(kp + (long)r*64 + src*8, (char*)Kd[0] + c*4096 + tid*16);
      g2lds16(vp + (long)r*1024 + src*8, (char*)Vd[0] + c*4096 + tid*16);
    }
    asm volatile("s_waitcnt vmcnt(0)" ::: "memory");
    __syncthreads();

    short8 aq[2][2];
    #pragma unroll
    for (int mf = 0; mf < 2; ++mf)
      #pragma unroll
      for (int kk = 0; kk < 2; ++kk){
        int r = wid*32 + mf*16 + n15;
        int sl = (kk*4 + l4) ^ (r & 7);
        aq[mf][kk] = *reinterpret_cast<const short8*>((const char*)Qs + r*128 + sl*16);
      }

    f32x4 o[2][4] = {};                           // cross = Q @ (pk^T*1024)
    #pragma unroll
    for (int kk = 0; kk < 2; ++kk){
      short8 bpk[4];
      #pragma unroll
      for (int nf = 0; nf < 4; ++nf){
        int r = nf*16 + n15;
        int sl = (kk*4 + l4) ^ (r & 7);
        bpk[nf] = *reinterpret_cast<const short8*>((const char*)Ps + r*128 + sl*16);
      }
      #pragma unroll
      for (int mf = 0; mf < 2; ++mf)
        #pragma unroll
        for (int nf = 0; nf < 4; ++nf)
          o[mf][nf] = __builtin_amdgcn_mfma_f32_16x16x32_bf16(aq[mf][kk], bpk[nf], o[mf][nf], 0,0,0);
    }
    __syncthreads();                              // Ps free for P-writes after this

    const int jmax = 2*qt + 1;
    int cur = 0;
    for (int j = 0; j <= jmax; ++j){
      const int kv0 = j*64;
      if (j < jmax){                              // prefetch next K/V tile
        const int kvn = kv0 + 64;
        for (int c = 0; c < 2; ++c){
          int r = c*32 + srow;
          int src = schunk ^ (r & 7);
          g2lds16(kp + (long)(kvn + r)*64 + src*8, (char*)Kd[cur^1] + c*4096 + tid*16);
          g2lds16(vp + (long)r*1024 + kvn + src*8, (char*)Vd[cur^1] + c*4096 + tid*16);
        }
      }
      // S = Q K^T
      f32x4 s[2][4] = {};
      #pragma unroll
      for (int kk = 0; kk < 2; ++kk){
        short8 bk[4];
        #pragma unroll
        for (int nf = 0; nf < 4; ++nf){
          int r = nf*16 + n15;
          int sl = (kk*4 + l4) ^ (r & 7);
          bk[nf] = *reinterpret_cast<const short8*>((const char*)Kd[cur] + r*128 + sl*16);
        }
        #pragma unroll
        for (int mf = 0; mf < 2; ++mf)
          #pragma unroll
          for (int nf = 0; nf < 4; ++nf)
            s[mf][nf] = __builtin_amdgcn_mfma_f32_16x16x32_bf16(aq[mf][kk], bk[nf], s[mf][nf], 0,0,0);
      }
      // decay (factored) -> P
      float rowf[2][4];
      #pragma unroll
      for (int mf = 0; mf < 2; ++mf){
        int mB = wid*32 + mf*16 + l4*4;
        #pragma unroll
        for (int r = 0; r < 4; ++r)
          rowf[mf][r] = exp2f(lg * (float)(t0 + mB + r - kv0));
      }
      if (kv0 >= t0){                             // diagonal tiles: mask
        #pragma unroll
        for (int mf = 0; mf < 2; ++mf){
          int mB = wid*32 + mf*16 + l4*4;
          #pragma unroll
          for (int nf = 0; nf < 4; ++nf){
            int tj = kv0 + nf*16 + n15;
            int n = nf*16 + n15;
            #pragma unroll
            for (int r = 0; r < 4; ++r){
              int ti = t0 + mB + r;
              float val = (ti >= tj) ? s[mf][nf][r] * (rowf[mf][r] * cexp[nf]) : 0.0f;
              int byte = ((mB + r)*128 + n*2) ^ (((mB + r) & 7) << 4);
              *(unsigned short*)((char*)Ps + byte) = f2bf(val);
            }
          }
        }
      } else {                                    // strictly-causal tiles: no mask
        #pragma unroll
        for (int mf = 0; mf < 2; ++mf){
          int mB = wid*32 + mf*16 + l4*4;
          #pragma unroll
          for (int nf = 0; nf < 4; ++nf){
            int n = nf*16 + n15;
            #pragma unroll
            for (int r = 0; r < 4; ++r){
              float val = s[mf][nf][r] * (rowf[mf][r] * cexp[nf]);
              int byte = ((mB + r)*128 + n*2) ^ (((mB + r) & 7) << 4);
              *(unsigned short*)((char*)Ps + byte) = f2bf(val);
            }
          }
        }
      }
      // O += P @ V
      #pragma unroll
      for (int kk = 0; kk < 2; ++kk){
        short8 ap[2], bv[4];
        #pragma unroll
        for (int mf = 0; mf < 2; ++mf){
          int r = wid*32 + mf*16 + n15;
          int sl = (kk*4 + l4) ^ (r & 7);
          ap[mf] = *reinterpret_cast<const short8*>((const char*)Ps + r*128 + sl*16);
        }
        #pragma unroll
        for (int nf = 0; nf < 4; ++nf){
          int r = nf*16 + n15;
          int sl = (kk*4 + l4) ^ (r & 7);
          bv[nf] = *reinterpret_cast<const short8*>((const char*)Vd[cur] + r*128 + sl*16);
        }
        #pragma unroll
        for (int mf = 0; mf < 2; ++mf)
          #pragma unroll
          for (int nf = 0; nf < 4; ++nf)
            o[mf][nf] = __builtin_amdgcn_mfma_f32_16x16x32_bf16(ap[mf], bv[nf], o[mf][nf], 0,0,0);
      }
      asm volatile("s_waitcnt vmcnt(0)" ::: "memory");
      __syncthreads();
      cur ^= 1;
    }
    // epilogue: bf16 R + GN partial sums
    #pragma unroll
    for (int mf = 0; mf < 2; ++mf)
      #pragma unroll
      for (int nf = 0; nf < 4; ++nf)
        #pragma unroll
        for (int r = 0; r < 4; ++r){
          int t = t0 + wid*32 + mf*16 + l4*4 + r;
          int d = nf*16 + n15;
          float v = o[mf][nf][r];
          rp[t*64 + d] = f2bf(v);
          gs += v; gq += v*v;
        }
  }
  #pragma unroll
  for (int off = 32; off > 0; off >>= 1){
    gs += __shfl_down(gs, off);
    gq += __shfl_down(gq, off);
  }
  if (lane == 0){ gred[0][wid] = gs; gred[1][wid] = gq; }
  __syncthreads();
  if (tid == 0){
    gnp[(bh*4 + qpair)*2]   = gred[0][0]+gred[0][1]+gred[0][2]+gred[0][3];
    gnp[(bh*4 + qpair)*2+1] = gred[1][0]+gred[1][1]+gred[1][2]+gred[1][3];
  }
}

// ---------------- K^T V via MFMA (direct-global fragments) ----------------
__global__ __launch_bounds__(256) void k_kvpart(const unsigned short* __restrict__ ktb,
                                                const unsigned short* __restrict__ vtb,
                                                float* __restrict__ part){
  const int tw = blockIdx.x;                      // 0..1
  const int bh = blockIdx.y;
  const int tid = threadIdx.x;
  const int lane = tid & 63, wid = tid >> 6;
  const int n15 = lane & 15, l4 = lane >> 4;
  const unsigned short* kt = ktb + (long)bh*65536;
  const unsigned short* vt = vtb + (long)bh*65536;
  const int tb = tw*512 + wid*128;
  f32x4 acc[4][4] = {};
  for (int ks = 0; ks < 4; ++ks){
    const int toff = tb + ks*32 + l4*8;
    short8 a[4], b[4];
    #pragma unroll
    for (int i = 0; i < 4; ++i){
      a[i] = *reinterpret_cast<const short8*>(kt + (long)(i*16 + n15)*1024 + toff);
      b[i] = *reinterpret_cast<const short8*>(vt + (long)(i*16 + n15)*1024 + toff);
    }
    #pragma unroll
    for (int i = 0; i < 4; ++i)
      #pragma unroll
      for (int jn = 0; jn < 4; ++jn)
        acc[i][jn] = __builtin_amdgcn_mfma_f32_16x16x32_bf16(a[i], b[jn], acc[i][jn], 0,0,0);
  }
  float* pp = part + ((long)(bh*8 + tw*4 + wid) << 12);
  #pragma unroll
  for (int i = 0; i < 4; ++i)
    #pragma unroll
    for (int jn = 0; jn < 4; ++jn)
      #pragma unroll
      for (int r = 0; r < 4; ++r)
        pp[(i*16 + l4*4 + r)*64 + jn*16 + n15] = acc[i][jn][r];
}

__global__ __launch_bounds__(256) void k_kvfin(const float* __restrict__ part,
                                               const float* __restrict__ pk,
                                               float* __restrict__ okv){
  int i = blockIdx.x*256 + threadIdx.x;           // 65536
  int h = i >> 12, de = i & 4095;
  float acc = 0.f;
  for (int b = 0; b < 8; ++b){
    const float* pp = part + (((long)(b*16 + h)*8) << 12) + de;
    #pragma unroll
    for (int w = 0; w < 8; ++w) acc += pp[w*4096];
  }
  float gamma = 1.0f - exp2f(-5.0f - (float)h);
  okv[i] = gamma * pk[i] + acc * 0.125f;
}

// ---------------- GroupNorm finalize ----------------
__global__ __launch_bounds__(64) void k_gnr2(const float* __restrict__ gnp,
                                             float* __restrict__ musig){
  int b = threadIdx.x;
  if (b < 8){
    float S = 0.f, Q = 0.f;
    for (int g = 0; g < 64; ++g){ S += gnp[b*128 + g*2]; Q += gnp[b*128 + g*2 + 1]; }
    float mu  = S * (1.0f/1048576.0f);
    float var = Q * (1.0f/1048576.0f) - mu*mu;
    musig[b*2]   = mu;
    musig[b*2+1] = rsqrtf(var + 1e-5f);
  }
}

__global__ __launch_bounds__(256) void k_gnnorm(const unsigned short* __restrict__ rbuf,
                                                const float* __restrict__ musig,
                                                const float* __restrict__ gw,
                                                const float* __restrict__ gb,
                                                float* __restrict__ out){
  const int n8 = TKN*1024/8;
  for (int idx = blockIdx.x*256 + threadIdx.x; idx < n8; idx += gridDim.x*256){
    int o = idx*8;
    int c = o & 1023;
    int t = (o >> 10) & 1023;
    int b = o >> 20;
    int h = c >> 6, d = c & 63;
    short8 v = *reinterpret_cast<const short8*>(rbuf + ((long)(b*16 + h) << 16) + t*64 + d);
    float rs = musig[b*2+1];
    float a = gw[h]*rs, b2 = gb[h] - musig[b*2]*a;
    float4 o0, o1;
    o0.x = bf2f((unsigned short)v[0])*a + b2;
    o0.y = bf2f((unsigned short)v[1])*a + b2;
    o0.z = bf2f((unsigned short)v[2])*a + b2;
    o0.w = bf2f((unsigned short)v[3])*a + b2;
    o1.x = bf2f((unsigned short)v[4])*a + b2;
    o1.y = bf2f((unsigned short)v[5])*a + b2;
    o1.z = bf2f((unsigned short)v[6])*a + b2;
    o1.w = bf2f((unsigned short)v[7])*a + b2;
    *reinterpret_cast<float4*>(out + o)     = o0;
    *reinterpret_cast<float4*>(out + o + 4) = o1;
  }
}

extern "C" void kernel_launch(void* const* d_in, const int* in_sizes, int n_in,
                              void* d_out, int out_size, void* d_ws, size_t ws_size,
                              hipStream_t stream){
  const float* x  = (const float*)d_in[0];
  const float* pk = (const float*)d_in[1];
  const float* w  = (const float*)d_in[2];
  const float* gw = (const float*)d_in[3];
  const float* gb = (const float*)d_in[4];
  float* out = (float*)d_out;
  char* ws = (char*)d_ws;

  unsigned short* Xb  = (unsigned short*)(ws);                 // 16 MB (aliased by KVp later)
  unsigned short* WTb = (unsigned short*)(ws + 16777216);      //  6 MB
  unsigned short* Qb  = (unsigned short*)(ws + 23068672);      // 16 MB
  unsigned short* Kb  = (unsigned short*)(ws + 39845888);      // 16 MB
  unsigned short* VTb = (unsigned short*)(ws + 56623104);      // 16 MB
  unsigned short* KTb = (unsigned short*)(ws + 73400320);      // 16 MB
  unsigned short* PKt = (unsigned short*)(ws + 90177536);      // 128 KB
  unsigned short* Rb  = (unsigned short*)(ws + 90308608);      // 16 MB (bf16)
  float* KVp = (float*)(ws);                                   // 16 MB, aliases Xb (dead after gemm)
  float* GNp = (float*)(ws + 107085824);                       // 4 KB
  float* MuS = (float*)(ws + 107089920);                       // 64 B

  k_cvt_x  <<<dim3(2048),    dim3(256), 0, stream>>>(x, Xb);
  k_cvt_w  <<<dim3(48, 16),  dim3(256), 0, stream>>>(w, WTb);
  k_cvt_pk <<<dim3(256),     dim3(256), 0, stream>>>(pk, PKt);
  k_gemm   <<<dim3(24, 64),  dim3(256), 0, stream>>>(Xb, WTb, Qb, Kb, KTb, VTb);
  k_attn   <<<dim3(4, 128),  dim3(256), 0, stream>>>(Qb, Kb, VTb, PKt, Rb, GNp);
  k_kvpart <<<dim3(2, 128),  dim3(256), 0, stream>>>(KTb, VTb, KVp);
  k_kvfin  <<<dim3(256),     dim3(256), 0, stream>>>(KVp, pk, out + 8388608);
  k_gnr2   <<<dim3(1),       dim3(64),  0, stream>>>(GNp, MuS);
  k_gnnorm <<<dim3(1024),    dim3(256), 0, stream>>>(Rb, MuS, gw, gb, out);
}